// Round 3
// baseline (238.070 us; speedup 1.0000x reference)
//
#include <hip/hip_runtime.h>

#define NN 16
#define DD 64
#define SS 32
#define MM 48
// output element (n,s,i,j,k) at ((n*SS+s)*MM + i)*MM*MM + j*MM + k

typedef float floatx4 __attribute__((ext_vector_type(4)));

__global__ __launch_bounds__(576, 1) void eq1to3_kernel(
    const float* __restrict__ x,      // (N, D, M)
    const float* __restrict__ coefs,  // (D, S, 4)
    const float* __restrict__ bias,   // (1, S, 1, 1, 1) -> [S]
    float* __restrict__ out)          // (N, S, M, M, M)
{
    __shared__ float t_lds[4][MM];    // t[b][m] for this (n,s)

    const int ns = blockIdx.x;        // 0..511
    const int n  = ns / SS;
    const int s  = ns % SS;
    const int tid = threadIdx.x;      // 0..575

    // ---- Phase 1: t[b][m] = sum_d coefs[d,s,b] * x[n,d,m]  (tiny) ----
    if (tid < 4 * MM) {
        const int m = tid % MM;
        const int b = tid / MM;
        const float* xp = x + (size_t)n * DD * MM + m;
        const float* cp = coefs + s * 4 + b;
        float acc = 0.f;
        #pragma unroll 8
        for (int d = 0; d < DD; ++d) {
            acc += cp[(size_t)d * SS * 4] * xp[(size_t)d * MM];
        }
        t_lds[b][m] = acc;
    }
    __syncthreads();

    // ---- Phase 2: broadcast-expand + non-temporal streaming store ----
    // thread owns (j, k4). Per i the block stores one contiguous 9216 B
    // plane (per wave: 64 lanes x 16 B = 1024 B contiguous). i is
    // WAVE-UNIFORM: trip count identical across lanes -> full coalescing.
    const int j  = tid / (MM / 4);    // 0..47
    const int k4 = tid % (MM / 4);    // 0..11

    const float bs  = bias[s];
    const float t1j = t_lds[1][j];
    floatx4 base;
    base.x = t_lds[2][4 * k4 + 0] + t1j + bs;
    base.y = t_lds[2][4 * k4 + 1] + t1j + bs;
    base.z = t_lds[2][4 * k4 + 2] + t1j + bs;
    base.w = t_lds[2][4 * k4 + 3] + t1j + bs;

    // superdiagonal add vector: nonzero only for the thread whose k-quad
    // contains k == j; applied when i == j (exec-masked, no branch cost).
    floatx4 dvec = {0.f, 0.f, 0.f, 0.f};
    if ((j >> 2) == k4) dvec[j & 3] = t_lds[3][j];

    floatx4* outp = (floatx4*)(out + (size_t)ns * MM * MM * MM + j * MM + 4 * k4);
    const int plane4 = MM * MM / 4;   // 576 float4 per i-plane

    #pragma unroll 4
    for (int i = 0; i < MM; ++i) {
        const float t0i = t_lds[0][i];   // uniform address -> LDS broadcast
        floatx4 v = base + t0i;
        if (i == j) v += dvec;           // 12 lanes/wave, exec-masked adds
        __builtin_nontemporal_store(v, outp + (size_t)i * plane4);
    }
}

extern "C" void kernel_launch(void* const* d_in, const int* in_sizes, int n_in,
                              void* d_out, int out_size, void* d_ws, size_t ws_size,
                              hipStream_t stream) {
    const float* x     = (const float*)d_in[0];
    const float* coefs = (const float*)d_in[1];
    const float* bias  = (const float*)d_in[2];
    float* out = (float*)d_out;

    eq1to3_kernel<<<dim3(NN * SS), dim3(576), 0, stream>>>(x, coefs, bias, out);
}

// Round 6
// 224.784 us; speedup vs baseline: 1.0591x; 1.0591x over previous
//
#include <hip/hip_runtime.h>

#define NN 16
#define DD 64
#define SS 32
#define MM 48
// output element (n,s,i,j,k) at ((n*SS+s)*MM + i)*MM*MM + j*MM + k

typedef float floatx4 __attribute__((ext_vector_type(4)));

__global__ __launch_bounds__(576, 1) void eq1to3_kernel(
    const float* __restrict__ x,      // (N, D, M)
    const float* __restrict__ coefs,  // (D, S, 4)
    const float* __restrict__ bias,   // (1, S, 1, 1, 1) -> [S]
    float* __restrict__ out)          // (N, S, M, M, M)
{
    __shared__ float t_lds[4][MM];    // t[b][m] for this (n,s)

    const int ns = blockIdx.x;        // 0..511
    const int n  = ns / SS;
    const int s  = ns % SS;
    const int tid = threadIdx.x;      // 0..575

    // ---- Phase 1: t[b][m] = sum_d coefs[d,s,b] * x[n,d,m]  (tiny) ----
    if (tid < 4 * MM) {
        const int m = tid % MM;
        const int b = tid / MM;
        const float* xp = x + (size_t)n * DD * MM + m;
        const float* cp = coefs + s * 4 + b;
        float acc = 0.f;
        #pragma unroll 8
        for (int d = 0; d < DD; ++d) {
            acc += cp[(size_t)d * SS * 4] * xp[(size_t)d * MM];
        }
        t_lds[b][m] = acc;
    }
    __syncthreads();

    // ---- Phase 2: broadcast-expand + PLAIN cached stores ----
    // (r2/r3 used __builtin_nontemporal_store and both capped at ~2.5 TB/s;
    //  the 906 MB poison fill sustains 6.2 TB/s with plain stores -> A/B the
    //  store path, everything else unchanged.)
    // thread owns (j, k4). Per i the block stores one contiguous 9216 B
    // plane (per wave: 64 lanes x 16 B = 1024 B contiguous). i is
    // WAVE-UNIFORM: trip count identical across lanes -> full coalescing.
    const int j  = tid / (MM / 4);    // 0..47
    const int k4 = tid % (MM / 4);    // 0..11

    const float bs  = bias[s];
    const float t1j = t_lds[1][j];
    floatx4 base;
    base.x = t_lds[2][4 * k4 + 0] + t1j + bs;
    base.y = t_lds[2][4 * k4 + 1] + t1j + bs;
    base.z = t_lds[2][4 * k4 + 2] + t1j + bs;
    base.w = t_lds[2][4 * k4 + 3] + t1j + bs;

    // superdiagonal add vector: nonzero only for the thread whose k-quad
    // contains k == j; applied when i == j (exec-masked, no branch cost).
    floatx4 dvec = {0.f, 0.f, 0.f, 0.f};
    if ((j >> 2) == k4) dvec[j & 3] = t_lds[3][j];

    floatx4* outp = (floatx4*)(out + (size_t)ns * MM * MM * MM + j * MM + 4 * k4);
    const int plane4 = MM * MM / 4;   // 576 float4 per i-plane

    #pragma unroll 4
    for (int i = 0; i < MM; ++i) {
        const float t0i = t_lds[0][i];   // uniform address -> LDS broadcast
        floatx4 v = base + t0i;
        if (i == j) v += dvec;           // 12 lanes/wave, exec-masked adds
        outp[(size_t)i * plane4] = v;    // plain store (L2 write-allocate)
    }
}

extern "C" void kernel_launch(void* const* d_in, const int* in_sizes, int n_in,
                              void* d_out, int out_size, void* d_ws, size_t ws_size,
                              hipStream_t stream) {
    const float* x     = (const float*)d_in[0];
    const float* coefs = (const float*)d_in[1];
    const float* bias  = (const float*)d_in[2];
    float* out = (float*)d_out;

    eq1to3_kernel<<<dim3(NN * SS), dim3(576), 0, stream>>>(x, coefs, bias, out);
}

// Round 7
// 221.988 us; speedup vs baseline: 1.0724x; 1.0126x over previous
//
#include <hip/hip_runtime.h>

#define NN 16
#define DD 64
#define SS 32
#define MM 48
#define NSB (NN*SS)            // 512 (n,s) pairs
#define TBL (NSB*MM)           // 24576 floats per t-table
// out float4-index f = ns*27648 + i*576 + j*12 + k4

typedef float floatx4 __attribute__((ext_vector_type(4)));

// ---- Kernel 1: t[b][ns][m] = sum_d coefs[d,s,b] * x[n,d,m]; bias folded into t1 ----
__global__ __launch_bounds__(192, 1) void eq1to3_tk(
    const float* __restrict__ x,      // (N, D, M)
    const float* __restrict__ coefs,  // (D, S, 4)
    const float* __restrict__ bias,   // [S]
    float* __restrict__ t)            // ws: 4 tables of [512][48] floats
{
    const int ns = blockIdx.x;        // 0..511
    const int n  = ns / SS;
    const int s  = ns % SS;
    const int b  = threadIdx.x / MM;  // 0..3
    const int m  = threadIdx.x % MM;  // 0..47

    const float* xp = x + (size_t)n * DD * MM + m;
    const float* cp = coefs + s * 4 + b;
    float acc = 0.f;
    #pragma unroll 8
    for (int d = 0; d < DD; ++d)
        acc += cp[(size_t)d * SS * 4] * xp[(size_t)d * MM];

    if (b == 1) acc += bias[s];       // fold bias into t1
    t[b * TBL + ns * MM + m] = acc;
}

// ---- Kernel 2: fill-shaped pure expansion. 256-thread blocks, linear float4
// per lane (1 KiB contiguous per wave, contiguous across blocks), 4-deep
// stride loop where only ns changes (+128) so the decode is amortized. ----
__global__ __launch_bounds__(256, 1) void eq1to3_store(
    const float* __restrict__ t,
    float* __restrict__ out)
{
    const unsigned g = blockIdx.x * 256u + threadIdx.x;   // 0 .. 3,538,943
    const unsigned k4  = g % 12u;
    const unsigned r1  = g / 12u;
    const unsigned j   = r1 % (unsigned)MM;
    const unsigned r2  = r1 / (unsigned)MM;
    const unsigned i   = r2 % (unsigned)MM;
    const unsigned ns0 = r2 / (unsigned)MM;               // 0..127

    const float*   t0  = t;                                // [ns][i]
    const float*   t1  = t + TBL;                          // [ns][j], bias folded
    const floatx4* t2q = (const floatx4*)(t + 2 * TBL);    // [ns][12]
    const float*   t3  = t + 3 * TBL;                      // [ns][m]

    const bool diag = (i == j) && ((j >> 2) == k4);
    const int  dl   = j & 3;
    floatx4* out4 = (floatx4*)out;

    #pragma unroll
    for (int p = 0; p < 4; ++p) {
        const unsigned ns = ns0 + 128u * p;
        floatx4 v = t2q[ns * 12u + k4];
        v += t0[ns * MM + i] + t1[ns * MM + j];
        if (diag) v[dl] += t3[ns * MM + j];
        out4[(size_t)ns * (MM*MM*MM/4) + i * (MM*MM/4) + j * (MM/4) + k4] = v;
    }
}

extern "C" void kernel_launch(void* const* d_in, const int* in_sizes, int n_in,
                              void* d_out, int out_size, void* d_ws, size_t ws_size,
                              hipStream_t stream) {
    const float* x     = (const float*)d_in[0];
    const float* coefs = (const float*)d_in[1];
    const float* bias  = (const float*)d_in[2];
    float* out = (float*)d_out;
    float* t   = (float*)d_ws;        // 4*24576*4 B = 393,216 B of scratch

    eq1to3_tk<<<dim3(NSB), dim3(192), 0, stream>>>(x, coefs, bias, t);
    eq1to3_store<<<dim3(NN*SS*MM*MM*MM/4/4/256), dim3(256), 0, stream>>>(t, out);
}